// Round 6
// baseline (1040.666 us; speedup 1.0000x reference)
//
#include <hip/hip_runtime.h>
#include <hip/hip_bf16.h>

// ---------------- problem constants ----------------
#define BATCH   32768
#define DIM     512
#define H1N     128
#define H2N     256
#define NSUB    20
#define HID     32
#define NCLS    100
#define NHID    640            // NSUB*HID
#define TOTALP  19716          // 512*32 + 32 + 32*100 + 100
#define NPAR    394320         // NSUB*TOTALP
#define WS1P    16384
#define WS1B1   16416          // WS1+BS1
#define WS2END  19616          // WS1+BS1+WS2

// ---------------- ws layout (float units) ----------------
#define OFF_PART 0              // 256*512 partial col sums
#define OFF_H    131584         // 256 f32 hypernet h
#define OFF_W    131840         // 32 f32 softmax(ens_w)
#define OFF_B1   131872         // 640 f32
#define OFF_BE   132512         // 128 f32 (unused now)
#define OFF_B2R  132640         // 2000 f32 raw b2
#define OFF_W1B  134640         // bf16 640*512   (163840 f32 slots)
#define OFF_W2B  298480         // bf16 128*640   (40960 f32 slots)
#define OFF_XB   339440         // bf16 32768*512 (8388608 f32 slots)
#define OFF_SYNC 8728048        // ints: prog[0..4], [8]=panel queue

// megakernel config
#define NPROD   320             // producer blocks
#define NBLK    512             // total blocks (co-resident: 2/CU x 256)
#define NPANEL  (BATCH / 64)    // 512 output panels
#define CHROWS  (4 * TOTALP)    // 78864 param rows per chunk

typedef __attribute__((ext_vector_type(8))) short short8;
typedef __attribute__((ext_vector_type(4))) float f32x4;

static __device__ inline unsigned short f2bf(float f) {
    __hip_bfloat16 h = __float2bfloat16(f);
    return *reinterpret_cast<unsigned short*>(&h);
}

static __device__ __forceinline__ void gload16(const void* g, void* l) {
    __builtin_amdgcn_global_load_lds(
        (const __attribute__((address_space(1))) void*)g,
        (__attribute__((address_space(3))) void*)l, 16, 0, 0);
}

// ---------------- K1: partial column sums + bf16 convert of x (R2) ----------
__global__ __launch_bounds__(256) void k1_colsum(const float* __restrict__ x,
                                                 float* __restrict__ F) {
    int t = threadIdx.x, bid = blockIdx.x;
    const float* xb = x + (size_t)bid * 128 * DIM;
    unsigned short* ob = (unsigned short*)(F + OFF_XB) + (size_t)bid * 128 * DIM;
    float a0 = 0.f, a1 = 0.f;
    #pragma unroll 4
    for (int r = 0; r < 128; ++r) {
        float2 v = *(const float2*)(xb + r * DIM + t * 2);
        a0 += v.x; a1 += v.y;
        ushort2 u; u.x = f2bf(v.x); u.y = f2bf(v.y);
        *(ushort2*)(ob + r * DIM + t * 2) = u;
    }
    *(float2*)(F + OFF_PART + bid * DIM + t * 2) = make_float2(a0, a1);
}

// ---------------- K2: hypernet trunk (1 block) ----------
__global__ __launch_bounds__(256) void k2_hyper(
    const float* __restrict__ Wh1, const float* __restrict__ bh1,
    const float* __restrict__ g1,  const float* __restrict__ be1,
    const float* __restrict__ Wh2, const float* __restrict__ bh2,
    const float* __restrict__ g2,  const float* __restrict__ be2,
    const float* __restrict__ ensw, float* __restrict__ F)
{
    __shared__ __align__(16) float sctx[DIM];
    __shared__ __align__(16) float sP2[DIM];
    __shared__ __align__(16) float sh1[H1N];
    __shared__ __align__(16) float sh2[H2N];
    int t = threadIdx.x;

    // parallel partial reduce: float4 cols, b-range split across 2 halves
    {
        int c4 = (t & 127) * 4;
        int half = t >> 7;
        float4 a = make_float4(0.f, 0.f, 0.f, 0.f);
        #pragma unroll 8
        for (int b = half * 128; b < half * 128 + 128; ++b) {
            float4 v = *(const float4*)(F + OFF_PART + b * DIM + c4);
            a.x += v.x; a.y += v.y; a.z += v.z; a.w += v.w;
        }
        if (half == 0) *(float4*)(sP2 + c4) = a;
        __syncthreads();
        if (half == 1) {
            float4 o = *(const float4*)(sP2 + c4);
            o.x = (o.x + a.x) * (1.0f / BATCH);
            o.y = (o.y + a.y) * (1.0f / BATCH);
            o.z = (o.z + a.z) * (1.0f / BATCH);
            o.w = (o.w + a.w) * (1.0f / BATCH);
            *(float4*)(sctx + c4) = o;
        }
        __syncthreads();
    }

    if (t < H1N) {
        float v = bh1[t];
        const float4* w = (const float4*)(Wh1 + t * DIM);
        for (int k = 0; k < DIM / 4; ++k) {
            float4 ww = w[k]; float4 c = *(const float4*)(sctx + k * 4);
            v += ww.x * c.x + ww.y * c.y + ww.z * c.z + ww.w * c.w;
        }
        sh1[t] = v;
    }
    __syncthreads();
    {
        float mu = 0.f;
        for (int k = 0; k < H1N; ++k) mu += sh1[k];
        mu *= (1.0f / H1N);
        float var = 0.f;
        for (int k = 0; k < H1N; ++k) { float d = sh1[k] - mu; var += d * d; }
        var *= (1.0f / H1N);
        float inv = rsqrtf(var + 1e-5f);
        __syncthreads();
        if (t < H1N) {
            float v = (sh1[t] - mu) * inv * g1[t] + be1[t];
            sh1[t] = fmaxf(v, 0.f);
        }
        __syncthreads();
    }

    {
        float v = bh2[t];
        const float4* w = (const float4*)(Wh2 + t * H1N);
        for (int k = 0; k < H1N / 4; ++k) {
            float4 ww = w[k]; float4 c = *(const float4*)(sh1 + k * 4);
            v += ww.x * c.x + ww.y * c.y + ww.z * c.z + ww.w * c.w;
        }
        sh2[t] = v;
    }
    __syncthreads();
    {
        float mu = 0.f;
        for (int k = 0; k < H2N; ++k) mu += sh2[k];
        mu *= (1.0f / H2N);
        float var = 0.f;
        for (int k = 0; k < H2N; ++k) { float d = sh2[k] - mu; var += d * d; }
        var *= (1.0f / H2N);
        float inv = rsqrtf(var + 1e-5f);
        float v = (sh2[t] - mu) * inv * g2[t] + be2[t];
        F[OFF_H + t] = fmaxf(v, 0.f);
    }

    if (t == 0) {
        float m = -1e30f;
        for (int s = 0; s < NSUB; ++s) m = fmaxf(m, ensw[s]);
        float sum = 0.f, e[NSUB];
        for (int s = 0; s < NSUB; ++s) { e[s] = __expf(ensw[s] - m); sum += e[s]; }
        for (int s = 0; s < NSUB; ++s) F[OFF_W + s] = e[s] / sum;
    }
}

// ---------------- MEGA: producer (W_h3 GEMV+pack) || consumer (fused GEMM) --
__global__ __launch_bounds__(256, 2) void mega(
    const float* __restrict__ Wh3, const float* __restrict__ bh3,
    const __hip_bfloat16* __restrict__ XB, float* __restrict__ F,
    float* __restrict__ out)
{
    __shared__ __align__(16) unsigned char sA[64 * 128];    // 8 KB
    __shared__ __align__(16) unsigned char sB[128 * 128];   // 16 KB
    __shared__ __align__(16) unsigned char sP[64 * 256];    // 16 KB
    __shared__ int spn;

    const int t = threadIdx.x;
    int* SY = (int*)(F + OFF_SYNC);
    const __hip_bfloat16* W1B = (const __hip_bfloat16*)(F + OFF_W1B);
    const __hip_bfloat16* W2B = (const __hip_bfloat16*)(F + OFF_W2B);
    const int wid = t >> 6, lane = t & 63;
    const int l16 = lane & 15, lq = lane >> 4;

    // ================= producer phase =================
    if (blockIdx.x < NPROD) {
        int wv = blockIdx.x * 4 + wid;
        const float4 h = *(const float4*)(F + OFF_H + lane * 4);
        __hip_bfloat16* W1Bw = (__hip_bfloat16*)(F + OFF_W1B);
        __hip_bfloat16* W2Bw = (__hip_bfloat16*)(F + OFF_W2B);
        for (int n1 = 0; n1 < 5; ++n1) {
            int base = n1 * CHROWS;
            for (int p = base + wv; p < base + CHROWS; p += NPROD * 4) {
                const float4 w = *(const float4*)(Wh3 + (size_t)p * 256 + lane * 4);
                float d = w.x * h.x + w.y * h.y + w.z * h.z + w.w * h.w;
                for (int off = 32; off; off >>= 1) d += __shfl_down(d, off);
                if (lane == 0) {
                    float val = d + bh3[p];
                    int s = p / TOTALP;
                    int r = p - s * TOTALP;
                    if (r < WS1P) {
                        int hh = r >> 9, k = r & 511;
                        W1Bw[(s * HID + hh) * DIM + k] = __float2bfloat16(val);
                    } else if (r < WS1B1) {
                        F[OFF_B1 + s * HID + (r - WS1P)] = val;
                    } else if (r < WS2END) {
                        int q = r - WS1B1; int c = q >> 5, hh = q & 31;
                        float ws = F[OFF_W + s];
                        W2Bw[c * NHID + s * HID + hh] = __float2bfloat16(ws * val);
                    } else {
                        F[OFF_B2R + s * NCLS + (r - WS2END)] = val;
                    }
                }
            }
            __syncthreads();
            if (t == 0)
                __hip_atomic_fetch_add(&SY[n1], 1, __ATOMIC_RELEASE,
                                       __HIP_MEMORY_SCOPE_AGENT);
        }
    }

    // ================= consumer phase (all blocks) =================
    for (;;) {
        __syncthreads();
        if (t == 0)
            spn = __hip_atomic_fetch_add(&SY[8], 1, __ATOMIC_RELAXED,
                                         __HIP_MEMORY_SCOPE_AGENT);
        __syncthreads();
        int pn = spn;
        if (pn >= NPANEL) break;
        const int Row0 = pn * 64;

        f32x4 acc2[8];
        #pragma unroll
        for (int fn = 0; fn < 8; ++fn) acc2[fn] = (f32x4){0.f, 0.f, 0.f, 0.f};

        for (int n1 = 0; n1 < 5; ++n1) {
            // wait for chunk n1 params
            if (t == 0) {
                while (__hip_atomic_load(&SY[n1], __ATOMIC_ACQUIRE,
                                         __HIP_MEMORY_SCOPE_AGENT) < NPROD)
                    __builtin_amdgcn_s_sleep(8);
            }
            __syncthreads();

            f32x4 acc1[8];
            #pragma unroll
            for (int fn = 0; fn < 8; ++fn) acc1[fn] = (f32x4){0.f, 0.f, 0.f, 0.f};

            for (int kc = 0; kc < 512; kc += 64) {
                __syncthreads();
                #pragma unroll
                for (int i = 0; i < 2; ++i) {
                    int cidx = wid * 2 + i;
                    int ul = cidx * 64 + lane;
                    int row = ul >> 3, u = ul & 7;
                    gload16(XB + (size_t)(Row0 + row) * 512 + kc + ((u ^ (row & 7)) << 3),
                            sA + cidx * 1024);
                }
                #pragma unroll
                for (int i = 0; i < 4; ++i) {
                    int cidx = wid * 4 + i;
                    int ul = cidx * 64 + lane;
                    int row = ul >> 3, u = ul & 7;
                    gload16(W1B + (size_t)(n1 * 128 + row) * 512 + kc + ((u ^ (row & 7)) << 3),
                            sB + cidx * 1024);
                }
                __syncthreads();
                #pragma unroll
                for (int kk = 0; kk < 2; ++kk) {
                    int u = kk * 4 + lq;
                    int arow = wid * 16 + l16;
                    short8 af = *(const short8*)(sA + arow * 128 + ((u ^ (arow & 7)) << 4));
                    short8 bfv[8];
                    #pragma unroll
                    for (int fn = 0; fn < 8; ++fn) {
                        int rw = fn * 16 + l16;
                        bfv[fn] = *(const short8*)(sB + rw * 128 + ((u ^ (rw & 7)) << 4));
                    }
                    #pragma unroll
                    for (int fn = 0; fn < 8; ++fn)
                        acc1[fn] = __builtin_amdgcn_mfma_f32_16x16x32_bf16(
                            af, bfv[fn], acc1[fn], 0, 0, 0);
                }
            }

            // P = relu(acc1 + b1) -> bf16 -> sP (wave-private rows)
            #pragma unroll
            for (int fn = 0; fn < 8; ++fn) {
                int col = fn * 16 + l16;
                float b1v = F[OFF_B1 + n1 * 128 + col];
                int unit = col >> 3;
                #pragma unroll
                for (int r = 0; r < 4; ++r) {
                    int row = wid * 16 + lq * 4 + r;
                    float v = fmaxf(acc1[fn][r] + b1v, 0.f);
                    *(unsigned short*)(sP + row * 256 + ((unit ^ (row & 7)) << 4)
                                       + (col & 7) * 2) = f2bf(v);
                }
            }

            // stage-2: acc2 += P @ W2chunk^T
            #pragma unroll
            for (int kk2 = 0; kk2 < 2; ++kk2) {
                __syncthreads();
                #pragma unroll
                for (int i = 0; i < 4; ++i) {
                    int cidx = wid * 4 + i;
                    int ul = cidx * 64 + lane;
                    int row = ul >> 3, u = ul & 7;
                    gload16(W2B + (size_t)row * NHID + n1 * 128 + kk2 * 64
                                + ((u ^ (row & 7)) << 3),
                            sB + cidx * 1024);
                }
                __syncthreads();
                #pragma unroll
                for (int kk = 0; kk < 2; ++kk) {
                    int u = kk * 4 + lq;
                    int arow = wid * 16 + l16;
                    int unit = kk2 * 8 + u;
                    short8 af = *(const short8*)(sP + arow * 256 + ((unit ^ (arow & 7)) << 4));
                    short8 bfv[8];
                    #pragma unroll
                    for (int fn = 0; fn < 8; ++fn) {
                        int rw = fn * 16 + l16;
                        bfv[fn] = *(const short8*)(sB + rw * 128 + ((u ^ (rw & 7)) << 4));
                    }
                    #pragma unroll
                    for (int fn = 0; fn < 8; ++fn)
                        acc2[fn] = __builtin_amdgcn_mfma_f32_16x16x32_bf16(
                            af, bfv[fn], acc2[fn], 0, 0, 0);
                }
            }
        }

        // be = sum_s w_s * b2raw[s][col] into sBe (alias sA), then epilogue
        float* sBe = (float*)sA;
        __syncthreads();
        if (t < 128) {
            float b = 0.f;
            if (t < NCLS) {
                #pragma unroll
                for (int s = 0; s < NSUB; ++s)
                    b += F[OFF_W + s] * F[OFF_B2R + s * NCLS + t];
            }
            sBe[t] = b;
        }
        __syncthreads();

        #pragma unroll
        for (int fn = 0; fn < 8; ++fn) {
            int gcol = fn * 16 + l16;
            if (gcol < NCLS) {
                float be = sBe[gcol];
                #pragma unroll
                for (int r = 0; r < 4; ++r) {
                    int grow = Row0 + wid * 16 + lq * 4 + r;
                    out[(size_t)grow * NCLS + gcol] = acc2[fn][r] + be;
                }
            }
        }
    }
}

// ---------------- launch ----------------
extern "C" void kernel_launch(void* const* d_in, const int* in_sizes, int n_in,
                              void* d_out, int out_size, void* d_ws, size_t ws_size,
                              hipStream_t stream)
{
    const float* x    = (const float*)d_in[0];
    const float* Wh1  = (const float*)d_in[1];
    const float* bh1  = (const float*)d_in[2];
    const float* g1   = (const float*)d_in[3];
    const float* be1  = (const float*)d_in[4];
    const float* Wh2  = (const float*)d_in[5];
    const float* bh2  = (const float*)d_in[6];
    const float* g2   = (const float*)d_in[7];
    const float* be2  = (const float*)d_in[8];
    const float* Wh3  = (const float*)d_in[9];
    const float* bh3  = (const float*)d_in[10];
    const float* ensw = (const float*)d_in[11];
    float* F = (float*)d_ws;
    float* out = (float*)d_out;

    const __hip_bfloat16* XB = (const __hip_bfloat16*)(F + OFF_XB);

    // zero sync words (prog[0..4], panel queue) each launch
    hipMemsetAsync(F + OFF_SYNC, 0, 64 * sizeof(int), stream);

    k1_colsum<<<256, 256, 0, stream>>>(x, F);
    k2_hyper<<<1, 256, 0, stream>>>(Wh1, bh1, g1, be1, Wh2, bh2, g2, be2, ensw, F);
    mega<<<NBLK, 256, 0, stream>>>(Wh3, bh3, XB, F, out);
}

// Round 7
// 244.396 us; speedup vs baseline: 4.2581x; 4.2581x over previous
//
#include <hip/hip_runtime.h>
#include <hip/hip_bf16.h>

// ---------------- problem constants ----------------
#define BATCH   32768
#define DIM     512
#define H1N     128
#define H2N     256
#define NSUB    20
#define HID     32
#define NCLS    100
#define NHID    640            // NSUB*HID
#define TOTALP  19716          // 512*32 + 32 + 32*100 + 100
#define NPAR    394320         // NSUB*TOTALP
#define WS1P    16384
#define WS1B1   16416          // WS1+BS1
#define WS2END  19616          // WS1+BS1+WS2

// ---------------- ws layout (float units) ----------------
#define OFF_PART 0              // 256*512 partial col sums
#define OFF_H    131584         // 256 f32 hypernet h
#define OFF_W    131840         // 32 f32 softmax(ens_w)
#define OFF_B1   131872         // 640 f32
#define OFF_BE   132512         // 128 f32 (unused)
#define OFF_B2R  132640         // 2000 f32 raw b2
#define OFF_W1B  134640         // bf16 640*512   (163840 f32 slots)
#define OFF_W2B  298480         // bf16 128*640   (40960 f32 slots)
#define OFF_XB   339440         // bf16 32768*512 (8388608 f32 slots)

typedef __attribute__((ext_vector_type(8))) short short8;
typedef __attribute__((ext_vector_type(4))) float f32x4;

static __device__ inline unsigned short f2bf(float f) {
    __hip_bfloat16 h = __float2bfloat16(f);
    return *reinterpret_cast<unsigned short*>(&h);
}

static __device__ __forceinline__ void gload16(const void* g, void* l) {
    __builtin_amdgcn_global_load_lds(
        (const __attribute__((address_space(1))) void*)g,
        (__attribute__((address_space(3))) void*)l, 16, 0, 0);
}

// ---------------- K1: partial column sums + bf16 convert of x ----------
__global__ __launch_bounds__(256) void k1_colsum(const float* __restrict__ x,
                                                 float* __restrict__ F) {
    int t = threadIdx.x, bid = blockIdx.x;
    const float* xb = x + (size_t)bid * 128 * DIM;
    unsigned short* ob = (unsigned short*)(F + OFF_XB) + (size_t)bid * 128 * DIM;
    float a0 = 0.f, a1 = 0.f;
    #pragma unroll 4
    for (int r = 0; r < 128; ++r) {
        float2 v = *(const float2*)(xb + r * DIM + t * 2);
        a0 += v.x; a1 += v.y;
        ushort2 u; u.x = f2bf(v.x); u.y = f2bf(v.y);
        *(ushort2*)(ob + r * DIM + t * 2) = u;
    }
    *(float2*)(F + OFF_PART + bid * DIM + t * 2) = make_float2(a0, a1);
}

// ---------------- K2: hypernet trunk (1 block) ----------
__global__ __launch_bounds__(256) void k2_hyper(
    const float* __restrict__ Wh1, const float* __restrict__ bh1,
    const float* __restrict__ g1,  const float* __restrict__ be1,
    const float* __restrict__ Wh2, const float* __restrict__ bh2,
    const float* __restrict__ g2,  const float* __restrict__ be2,
    const float* __restrict__ ensw, float* __restrict__ F)
{
    __shared__ __align__(16) float sctx[DIM];
    __shared__ __align__(16) float sP2[DIM];
    __shared__ __align__(16) float sh1[H1N];
    __shared__ __align__(16) float sh2[H2N];
    int t = threadIdx.x;

    {
        int c4 = (t & 127) * 4;
        int half = t >> 7;
        float4 a = make_float4(0.f, 0.f, 0.f, 0.f);
        #pragma unroll 8
        for (int b = half * 128; b < half * 128 + 128; ++b) {
            float4 v = *(const float4*)(F + OFF_PART + b * DIM + c4);
            a.x += v.x; a.y += v.y; a.z += v.z; a.w += v.w;
        }
        if (half == 0) *(float4*)(sP2 + c4) = a;
        __syncthreads();
        if (half == 1) {
            float4 o = *(const float4*)(sP2 + c4);
            o.x = (o.x + a.x) * (1.0f / BATCH);
            o.y = (o.y + a.y) * (1.0f / BATCH);
            o.z = (o.z + a.z) * (1.0f / BATCH);
            o.w = (o.w + a.w) * (1.0f / BATCH);
            *(float4*)(sctx + c4) = o;
        }
        __syncthreads();
    }

    if (t < H1N) {
        float v = bh1[t];
        const float4* w = (const float4*)(Wh1 + t * DIM);
        for (int k = 0; k < DIM / 4; ++k) {
            float4 ww = w[k]; float4 c = *(const float4*)(sctx + k * 4);
            v += ww.x * c.x + ww.y * c.y + ww.z * c.z + ww.w * c.w;
        }
        sh1[t] = v;
    }
    __syncthreads();
    {
        float mu = 0.f;
        for (int k = 0; k < H1N; ++k) mu += sh1[k];
        mu *= (1.0f / H1N);
        float var = 0.f;
        for (int k = 0; k < H1N; ++k) { float d = sh1[k] - mu; var += d * d; }
        var *= (1.0f / H1N);
        float inv = rsqrtf(var + 1e-5f);
        __syncthreads();
        if (t < H1N) {
            float v = (sh1[t] - mu) * inv * g1[t] + be1[t];
            sh1[t] = fmaxf(v, 0.f);
        }
        __syncthreads();
    }

    {
        float v = bh2[t];
        const float4* w = (const float4*)(Wh2 + t * H1N);
        for (int k = 0; k < H1N / 4; ++k) {
            float4 ww = w[k]; float4 c = *(const float4*)(sh1 + k * 4);
            v += ww.x * c.x + ww.y * c.y + ww.z * c.z + ww.w * c.w;
        }
        sh2[t] = v;
    }
    __syncthreads();
    {
        float mu = 0.f;
        for (int k = 0; k < H2N; ++k) mu += sh2[k];
        mu *= (1.0f / H2N);
        float var = 0.f;
        for (int k = 0; k < H2N; ++k) { float d = sh2[k] - mu; var += d * d; }
        var *= (1.0f / H2N);
        float inv = rsqrtf(var + 1e-5f);
        float v = (sh2[t] - mu) * inv * g2[t] + be2[t];
        F[OFF_H + t] = fmaxf(v, 0.f);
    }

    if (t == 0) {
        float m = -1e30f;
        for (int s = 0; s < NSUB; ++s) m = fmaxf(m, ensw[s]);
        float sum = 0.f, e[NSUB];
        for (int s = 0; s < NSUB; ++s) { e[s] = __expf(ensw[s] - m); sum += e[s]; }
        for (int s = 0; s < NSUB; ++s) F[OFF_W + s] = e[s] / sum;
    }
}

// ---------------- K3: params GEMV fused with pack/convert (wave per row) -----
__global__ __launch_bounds__(256) void k3_gemv(
    const float* __restrict__ Wh3, const float* __restrict__ bh3, float* __restrict__ F)
{
    int t = threadIdx.x;
    int wid = t >> 6, lane = t & 63;
    int row = blockIdx.x * 4 + wid;   // < 394320
    const float4 h = *(const float4*)(F + OFF_H + lane * 4);
    const float4 w = *(const float4*)(Wh3 + (size_t)row * 256 + lane * 4);
    float d = w.x * h.x + w.y * h.y + w.z * h.z + w.w * h.w;
    for (int off = 32; off; off >>= 1) d += __shfl_down(d, off);
    if (lane == 0) {
        float val = d + bh3[row];
        int s = row / TOTALP;
        int r = row - s * TOTALP;
        __hip_bfloat16* W1B = (__hip_bfloat16*)(F + OFF_W1B);
        __hip_bfloat16* W2B = (__hip_bfloat16*)(F + OFF_W2B);
        if (r < WS1P) {
            int hh = r >> 9, k = r & 511;
            W1B[(s * HID + hh) * DIM + k] = __float2bfloat16(val);
        } else if (r < WS1B1) {
            F[OFF_B1 + s * HID + (r - WS1P)] = val;
        } else if (r < WS2END) {
            int q = r - WS1B1; int c = q >> 5, hh = q & 31;
            float ws = F[OFF_W + s];
            W2B[c * NHID + s * HID + hh] = __float2bfloat16(ws * val);
        } else {
            F[OFF_B2R + s * NCLS + (r - WS2END)] = val;
        }
    }
}

// ---------------- K5: fused dual GEMM, BM=128 ----------------
// Per block: 128 output rows, 4 waves, MR=2. For each of 5 chunks of 128 cols:
//   P = relu(XB_blk @ W1B_chunk^T + b1)  -> bf16 -> swizzled sP (128x128)
//   acc2 += P @ W2B_chunk^T              (K=128 in two 64-k sub-stages)
// out = acc2 + be(cols<100). HH never touches global memory.
__global__ __launch_bounds__(256, 2) void gemm_fused(
    const __hip_bfloat16* __restrict__ XB, const __hip_bfloat16* __restrict__ W1B,
    const __hip_bfloat16* __restrict__ W2B, const float* __restrict__ F,
    float* __restrict__ out)
{
    __shared__ __align__(16) unsigned char sA[128 * 128];   // 16 KB
    __shared__ __align__(16) unsigned char sB[128 * 128];   // 16 KB
    __shared__ __align__(16) unsigned char sP[128 * 256];   // 32 KB
    const int t = threadIdx.x;
    int bid = blockIdx.x;
    const int cpx = gridDim.x >> 3;
    bid = (bid & 7) * cpx + (bid >> 3);
    const int Row0 = bid * 128;
    const int wid = t >> 6, lane = t & 63;
    const int l16 = lane & 15, lq = lane >> 4;

    f32x4 acc2[2][8];
    #pragma unroll
    for (int fm = 0; fm < 2; ++fm)
        #pragma unroll
        for (int fn = 0; fn < 8; ++fn) acc2[fm][fn] = (f32x4){0.f, 0.f, 0.f, 0.f};

    for (int n1 = 0; n1 < 5; ++n1) {
        f32x4 acc1[2][8];
        #pragma unroll
        for (int fm = 0; fm < 2; ++fm)
            #pragma unroll
            for (int fn = 0; fn < 8; ++fn) acc1[fm][fn] = (f32x4){0.f, 0.f, 0.f, 0.f};

        for (int kc = 0; kc < 512; kc += 64) {
            __syncthreads();
            // A tile: 128 rows x 64 k (16 KB, 4 units/wave)
            #pragma unroll
            for (int i = 0; i < 4; ++i) {
                int cidx = wid * 4 + i;
                int ul = cidx * 64 + lane;
                int row = ul >> 3, u = ul & 7;
                gload16(XB + (size_t)(Row0 + row) * 512 + kc + ((u ^ (row & 7)) << 3),
                        sA + cidx * 1024);
            }
            // B1 tile: W1B rows n1*128..+128 x 64 k
            #pragma unroll
            for (int i = 0; i < 4; ++i) {
                int cidx = wid * 4 + i;
                int ul = cidx * 64 + lane;
                int row = ul >> 3, u = ul & 7;
                gload16(W1B + (size_t)(n1 * 128 + row) * 512 + kc + ((u ^ (row & 7)) << 3),
                        sB + cidx * 1024);
            }
            __syncthreads();
            #pragma unroll
            for (int kk = 0; kk < 2; ++kk) {
                int u = kk * 4 + lq;
                short8 af[2], bfv[8];
                #pragma unroll
                for (int fm = 0; fm < 2; ++fm) {
                    int arow = wid * 32 + fm * 16 + l16;
                    af[fm] = *(const short8*)(sA + arow * 128 + ((u ^ (arow & 7)) << 4));
                }
                #pragma unroll
                for (int fn = 0; fn < 8; ++fn) {
                    int rw = fn * 16 + l16;
                    bfv[fn] = *(const short8*)(sB + rw * 128 + ((u ^ (rw & 7)) << 4));
                }
                #pragma unroll
                for (int fm = 0; fm < 2; ++fm)
                    #pragma unroll
                    for (int fn = 0; fn < 8; ++fn)
                        acc1[fm][fn] = __builtin_amdgcn_mfma_f32_16x16x32_bf16(
                            af[fm], bfv[fn], acc1[fm][fn], 0, 0, 0);
            }
        }

        // P = relu(acc1 + b1) -> bf16 -> sP (wave-private rows wid*32..+32)
        #pragma unroll
        for (int fm = 0; fm < 2; ++fm) {
            #pragma unroll
            for (int fn = 0; fn < 8; ++fn) {
                int col = fn * 16 + l16;
                float b1v = F[OFF_B1 + n1 * 128 + col];
                int unit = col >> 3;
                #pragma unroll
                for (int r = 0; r < 4; ++r) {
                    int row = wid * 32 + fm * 16 + lq * 4 + r;
                    float v = fmaxf(acc1[fm][fn][r] + b1v, 0.f);
                    *(unsigned short*)(sP + row * 256 + ((unit ^ (row & 7)) << 4)
                                       + (col & 7) * 2) = f2bf(v);
                }
            }
        }

        // stage-2: acc2 += P @ W2chunk^T (K = 128 in two 64-k halves)
        #pragma unroll
        for (int kk2 = 0; kk2 < 2; ++kk2) {
            __syncthreads();   // all waves done with sB reads (and P written)
            #pragma unroll
            for (int i = 0; i < 4; ++i) {
                int cidx = wid * 4 + i;
                int ul = cidx * 64 + lane;
                int row = ul >> 3, u = ul & 7;
                gload16(W2B + (size_t)row * NHID + n1 * 128 + kk2 * 64
                            + ((u ^ (row & 7)) << 3),
                        sB + cidx * 1024);
            }
            __syncthreads();
            #pragma unroll
            for (int kk = 0; kk < 2; ++kk) {
                int u = kk * 4 + lq;
                int unit = kk2 * 8 + u;
                short8 af[2], bfv[8];
                #pragma unroll
                for (int fm = 0; fm < 2; ++fm) {
                    int arow = wid * 32 + fm * 16 + l16;
                    af[fm] = *(const short8*)(sP + arow * 256 + ((unit ^ (arow & 7)) << 4));
                }
                #pragma unroll
                for (int fn = 0; fn < 8; ++fn) {
                    int rw = fn * 16 + l16;
                    bfv[fn] = *(const short8*)(sB + rw * 128 + ((u ^ (rw & 7)) << 4));
                }
                #pragma unroll
                for (int fm = 0; fm < 2; ++fm)
                    #pragma unroll
                    for (int fn = 0; fn < 8; ++fn)
                        acc2[fm][fn] = __builtin_amdgcn_mfma_f32_16x16x32_bf16(
                            af[fm], bfv[fn], acc2[fm][fn], 0, 0, 0);
            }
        }
    }

    // be = sum_s w_s * b2raw[s][col] into sBe (alias sA), then epilogue
    float* sBe = (float*)sA;
    __syncthreads();
    if (t < 128) {
        float b = 0.f;
        if (t < NCLS) {
            #pragma unroll
            for (int s = 0; s < NSUB; ++s)
                b += F[OFF_W + s] * F[OFF_B2R + s * NCLS + t];
        }
        sBe[t] = b;
    }
    __syncthreads();

    #pragma unroll
    for (int fm = 0; fm < 2; ++fm) {
        #pragma unroll
        for (int fn = 0; fn < 8; ++fn) {
            int gcol = fn * 16 + l16;
            if (gcol < NCLS) {
                float be = sBe[gcol];
                #pragma unroll
                for (int r = 0; r < 4; ++r) {
                    int grow = Row0 + wid * 32 + fm * 16 + lq * 4 + r;
                    out[(size_t)grow * NCLS + gcol] = acc2[fm][fn][r] + be;
                }
            }
        }
    }
}

// ---------------- launch ----------------
extern "C" void kernel_launch(void* const* d_in, const int* in_sizes, int n_in,
                              void* d_out, int out_size, void* d_ws, size_t ws_size,
                              hipStream_t stream)
{
    const float* x    = (const float*)d_in[0];
    const float* Wh1  = (const float*)d_in[1];
    const float* bh1  = (const float*)d_in[2];
    const float* g1   = (const float*)d_in[3];
    const float* be1  = (const float*)d_in[4];
    const float* Wh2  = (const float*)d_in[5];
    const float* bh2  = (const float*)d_in[6];
    const float* g2   = (const float*)d_in[7];
    const float* be2  = (const float*)d_in[8];
    const float* Wh3  = (const float*)d_in[9];
    const float* bh3  = (const float*)d_in[10];
    const float* ensw = (const float*)d_in[11];
    float* F = (float*)d_ws;
    float* out = (float*)d_out;

    const __hip_bfloat16* XB  = (const __hip_bfloat16*)(F + OFF_XB);
    const __hip_bfloat16* W1B = (const __hip_bfloat16*)(F + OFF_W1B);
    const __hip_bfloat16* W2B = (const __hip_bfloat16*)(F + OFF_W2B);

    k1_colsum<<<256, 256, 0, stream>>>(x, F);
    k2_hyper<<<1, 256, 0, stream>>>(Wh1, bh1, g1, be1, Wh2, bh2, g2, be2, ensw, F);
    k3_gemv<<<NPAR / 4, 256, 0, stream>>>(Wh3, bh3, F);
    // fused: out = relu(XB @ W1B^T + b1) @ W2B^T + be   M=32768, grid 256 x BM=128
    gemm_fused<<<BATCH / 128, 256, 0, stream>>>(XB, W1B, W2B, F, out);
}

// Round 8
// 193.846 us; speedup vs baseline: 5.3685x; 1.2608x over previous
//
#include <hip/hip_runtime.h>
#include <hip/hip_bf16.h>

// ---------------- problem constants ----------------
#define BATCH   32768
#define DIM     512
#define H1N     128
#define H2N     256
#define NSUB    20
#define HID     32
#define NCLS    100
#define NHID    640            // NSUB*HID
#define TOTALP  19716          // 512*32 + 32 + 32*100 + 100
#define NPAR    394320         // NSUB*TOTALP
#define WS1P    16384
#define WS1B1   16416          // WS1+BS1
#define WS2END  19616          // WS1+BS1+WS2

// ---------------- ws layout (float units) ----------------
#define OFF_PART 0              // 512*512 partial col sums
#define OFF_H    262144         // 256 f32 hypernet h
#define OFF_W    262400         // 32 f32 softmax(ens_w)
#define OFF_B1   262432         // 640 f32
#define OFF_B2R  263072         // 2000 f32 raw b2
#define OFF_W1B  265072         // bf16 640*512   (163840 f32 slots)
#define OFF_W2B  428912         // bf16 128*640   (40960 f32 slots)
#define OFF_XB   469872         // bf16 32768*512 (8388608 f32 slots)

typedef __attribute__((ext_vector_type(8))) short short8;
typedef __attribute__((ext_vector_type(4))) float f32x4;

static __device__ inline unsigned short f2bf(float f) {
    __hip_bfloat16 h = __float2bfloat16(f);
    return *reinterpret_cast<unsigned short*>(&h);
}

static __device__ __forceinline__ void gload16(const void* g, void* l) {
    __builtin_amdgcn_global_load_lds(
        (const __attribute__((address_space(1))) void*)g,
        (__attribute__((address_space(3))) void*)l, 16, 0, 0);
}

// ---------------- K1: partial column sums + bf16 convert of x ----------------
// 512 blocks x 64 rows; float4 per thread; parity split for independent iters.
__global__ __launch_bounds__(256) void k1_colsum(const float* __restrict__ x,
                                                 float* __restrict__ F) {
    __shared__ float sP[DIM];
    int t = threadIdx.x, bid = blockIdx.x;
    int par = t >> 7;            // 0 or 1
    int c4 = (t & 127) * 4;
    const float* xb = x + (size_t)bid * 64 * DIM;
    unsigned short* ob = (unsigned short*)(F + OFF_XB) + (size_t)bid * 64 * DIM;
    float4 acc = make_float4(0.f, 0.f, 0.f, 0.f);
    #pragma unroll 8
    for (int i = 0; i < 32; ++i) {
        int r = 2 * i + par;
        float4 v = *(const float4*)(xb + r * DIM + c4);
        acc.x += v.x; acc.y += v.y; acc.z += v.z; acc.w += v.w;
        ushort4 u;
        u.x = f2bf(v.x); u.y = f2bf(v.y); u.z = f2bf(v.z); u.w = f2bf(v.w);
        *(ushort4*)(ob + r * DIM + c4) = u;
    }
    if (par == 0) *(float4*)(sP + c4) = acc;
    __syncthreads();
    if (par == 1) {
        float4 p = *(const float4*)(sP + c4);
        p.x += acc.x; p.y += acc.y; p.z += acc.z; p.w += acc.w;
        *(float4*)(F + OFF_PART + bid * DIM + c4) = p;
    }
}

// ---------------- K2: hypernet trunk (1 block) ----------
__global__ __launch_bounds__(256) void k2_hyper(
    const float* __restrict__ Wh1, const float* __restrict__ bh1,
    const float* __restrict__ g1,  const float* __restrict__ be1,
    const float* __restrict__ Wh2, const float* __restrict__ bh2,
    const float* __restrict__ g2,  const float* __restrict__ be2,
    const float* __restrict__ ensw, float* __restrict__ F)
{
    __shared__ __align__(16) float sctx[DIM];
    __shared__ __align__(16) float sP2[DIM];
    __shared__ __align__(16) float sh1[H1N];
    __shared__ __align__(16) float sh2[H2N];
    int t = threadIdx.x;

    // reduce 512 partial rows: float4 cols, b-range split across 2 halves
    {
        int c4 = (t & 127) * 4;
        int half = t >> 7;
        float4 a = make_float4(0.f, 0.f, 0.f, 0.f);
        #pragma unroll 8
        for (int b = half * 256; b < half * 256 + 256; ++b) {
            float4 v = *(const float4*)(F + OFF_PART + b * DIM + c4);
            a.x += v.x; a.y += v.y; a.z += v.z; a.w += v.w;
        }
        if (half == 0) *(float4*)(sP2 + c4) = a;
        __syncthreads();
        if (half == 1) {
            float4 o = *(const float4*)(sP2 + c4);
            o.x = (o.x + a.x) * (1.0f / BATCH);
            o.y = (o.y + a.y) * (1.0f / BATCH);
            o.z = (o.z + a.z) * (1.0f / BATCH);
            o.w = (o.w + a.w) * (1.0f / BATCH);
            *(float4*)(sctx + c4) = o;
        }
        __syncthreads();
    }

    if (t < H1N) {
        float v = bh1[t];
        const float4* w = (const float4*)(Wh1 + t * DIM);
        for (int k = 0; k < DIM / 4; ++k) {
            float4 ww = w[k]; float4 c = *(const float4*)(sctx + k * 4);
            v += ww.x * c.x + ww.y * c.y + ww.z * c.z + ww.w * c.w;
        }
        sh1[t] = v;
    }
    __syncthreads();
    {
        float mu = 0.f;
        for (int k = 0; k < H1N; ++k) mu += sh1[k];
        mu *= (1.0f / H1N);
        float var = 0.f;
        for (int k = 0; k < H1N; ++k) { float d = sh1[k] - mu; var += d * d; }
        var *= (1.0f / H1N);
        float inv = rsqrtf(var + 1e-5f);
        __syncthreads();
        if (t < H1N) {
            float v = (sh1[t] - mu) * inv * g1[t] + be1[t];
            sh1[t] = fmaxf(v, 0.f);
        }
        __syncthreads();
    }

    {
        float v = bh2[t];
        const float4* w = (const float4*)(Wh2 + t * H1N);
        for (int k = 0; k < H1N / 4; ++k) {
            float4 ww = w[k]; float4 c = *(const float4*)(sh1 + k * 4);
            v += ww.x * c.x + ww.y * c.y + ww.z * c.z + ww.w * c.w;
        }
        sh2[t] = v;
    }
    __syncthreads();
    {
        float mu = 0.f;
        for (int k = 0; k < H2N; ++k) mu += sh2[k];
        mu *= (1.0f / H2N);
        float var = 0.f;
        for (int k = 0; k < H2N; ++k) { float d = sh2[k] - mu; var += d * d; }
        var *= (1.0f / H2N);
        float inv = rsqrtf(var + 1e-5f);
        float v = (sh2[t] - mu) * inv * g2[t] + be2[t];
        F[OFF_H + t] = fmaxf(v, 0.f);
    }

    if (t == 0) {
        float m = -1e30f;
        for (int s = 0; s < NSUB; ++s) m = fmaxf(m, ensw[s]);
        float sum = 0.f, e[NSUB];
        for (int s = 0; s < NSUB; ++s) { e[s] = __expf(ensw[s] - m); sum += e[s]; }
        for (int s = 0; s < NSUB; ++s) F[OFF_W + s] = e[s] / sum;
    }
}

// ---------------- K3: params GEMV fused with pack/convert --------------------
// 2 rows per wave (back-to-back 1KB loads, interleaved reduce chains).
static __device__ __forceinline__ void k3_pack(float* F, int row, float val) {
    __hip_bfloat16* W1B = (__hip_bfloat16*)(F + OFF_W1B);
    __hip_bfloat16* W2B = (__hip_bfloat16*)(F + OFF_W2B);
    int s = row / TOTALP;
    int r = row - s * TOTALP;
    if (r < WS1P) {
        int hh = r >> 9, k = r & 511;
        W1B[(s * HID + hh) * DIM + k] = __float2bfloat16(val);
    } else if (r < WS1B1) {
        F[OFF_B1 + s * HID + (r - WS1P)] = val;
    } else if (r < WS2END) {
        int q = r - WS1B1; int c = q >> 5, hh = q & 31;
        float ws = F[OFF_W + s];
        W2B[c * NHID + s * HID + hh] = __float2bfloat16(ws * val);
    } else {
        F[OFF_B2R + s * NCLS + (r - WS2END)] = val;
    }
}

__global__ __launch_bounds__(256) void k3_gemv(
    const float* __restrict__ Wh3, const float* __restrict__ bh3, float* __restrict__ F)
{
    int t = threadIdx.x;
    int wid = t >> 6, lane = t & 63;
    int row0 = blockIdx.x * 8 + wid * 2;   // 2 rows per wave
    const float4 h = *(const float4*)(F + OFF_H + lane * 4);
    const float4 w0 = *(const float4*)(Wh3 + (size_t)row0 * 256 + lane * 4);
    const float4 w1 = *(const float4*)(Wh3 + (size_t)(row0 + 1) * 256 + lane * 4);
    float d0 = w0.x * h.x + w0.y * h.y + w0.z * h.z + w0.w * h.w;
    float d1 = w1.x * h.x + w1.y * h.y + w1.z * h.z + w1.w * h.w;
    #pragma unroll
    for (int off = 32; off; off >>= 1) {
        d0 += __shfl_down(d0, off);
        d1 += __shfl_down(d1, off);
    }
    if (lane == 0) {
        k3_pack(F, row0,     d0 + bh3[row0]);
        k3_pack(F, row0 + 1, d1 + bh3[row0 + 1]);
    }
}

// ---------------- K5: fused dual GEMM, BM=64, BK=128 ----------------
// Per block: 64 output rows, 4 waves. For each of 5 chunks of 128 HH-cols:
//   stage1: 4 K-steps of BK=128 (sA 16KB + sB 32KB per step, 1 barrier pair)
//   P = relu(acc1+b1) -> bf16 -> swizzled sP (64x256B)
//   stage2: one 32KB W2-chunk stage + 1 barrier pair, K=128 MFMA
// out = acc2 + be(cols<100), be computed in epilogue from OFF_W x OFF_B2R.
__global__ __launch_bounds__(256) void gemm_fused(
    const __hip_bfloat16* __restrict__ XB, const __hip_bfloat16* __restrict__ W1B,
    const __hip_bfloat16* __restrict__ W2B, const float* __restrict__ F,
    float* __restrict__ out)
{
    __shared__ __align__(16) unsigned char sA[64 * 256];    // 16 KB (64 rows x 128k)
    __shared__ __align__(16) unsigned char sB[128 * 256];   // 32 KB (128 rows x 128k)
    __shared__ __align__(16) unsigned char sP[64 * 256];    // 16 KB (64 rows x 128 cols)
    const int t = threadIdx.x;
    int bid = blockIdx.x;
    const int cpx = gridDim.x >> 3;
    bid = (bid & 7) * cpx + (bid >> 3);
    const int Row0 = bid * 64;
    const int wid = t >> 6, lane = t & 63;
    const int l16 = lane & 15, lq = lane >> 4;

    f32x4 acc2[8];
    #pragma unroll
    for (int fn = 0; fn < 8; ++fn) acc2[fn] = (f32x4){0.f, 0.f, 0.f, 0.f};

    for (int n1 = 0; n1 < 5; ++n1) {
        f32x4 acc1[8];
        #pragma unroll
        for (int fn = 0; fn < 8; ++fn) acc1[fn] = (f32x4){0.f, 0.f, 0.f, 0.f};

        for (int kc = 0; kc < 512; kc += 128) {
            __syncthreads();
            // A tile: 64 rows x 128 k (16 units/row), 4 units/thread
            #pragma unroll
            for (int i = 0; i < 4; ++i) {
                int ul = (wid * 4 + i) * 64 + lane;
                int row = ul >> 4, u = ul & 15;
                gload16(XB + (size_t)(Row0 + row) * 512 + kc + ((u ^ (row & 7)) << 3),
                        sA + (wid * 4 + i) * 1024);
            }
            // B1 tile: 128 rows x 128 k, 8 units/thread
            #pragma unroll
            for (int i = 0; i < 8; ++i) {
                int ul = (wid * 8 + i) * 64 + lane;
                int row = ul >> 4, u = ul & 15;
                gload16(W1B + (size_t)(n1 * 128 + row) * 512 + kc + ((u ^ (row & 7)) << 3),
                        sB + (wid * 8 + i) * 1024);
            }
            __syncthreads();
            #pragma unroll
            for (int kk = 0; kk < 4; ++kk) {
                int u = kk * 4 + lq;
                int arow = wid * 16 + l16;
                short8 af = *(const short8*)(sA + arow * 256 + ((u ^ (arow & 7)) << 4));
                short8 bfv[8];
                #pragma unroll
                for (int fn = 0; fn < 8; ++fn) {
                    int rw = fn * 16 + l16;
                    bfv[fn] = *(const short8*)(sB + rw * 256 + ((u ^ (rw & 7)) << 4));
                }
                #pragma unroll
                for (int fn = 0; fn < 8; ++fn)
                    acc1[fn] = __builtin_amdgcn_mfma_f32_16x16x32_bf16(
                        af, bfv[fn], acc1[fn], 0, 0, 0);
            }
        }

        // P = relu(acc1 + b1) -> bf16 -> sP (wave-private rows wid*16..+16)
        #pragma unroll
        for (int fn = 0; fn < 8; ++fn) {
            int col = fn * 16 + l16;
            float b1v = F[OFF_B1 + n1 * 128 + col];
            int unit = col >> 3;
            #pragma unroll
            for (int r = 0; r < 4; ++r) {
                int row = wid * 16 + lq * 4 + r;
                float v = fmaxf(acc1[fn][r] + b1v, 0.f);
                *(unsigned short*)(sP + row * 256 + ((unit ^ (row & 7)) << 4)
                                   + (col & 7) * 2) = f2bf(v);
            }
        }

        // stage-2: acc2 += P @ W2chunk^T, one 32KB stage, K=128
        __syncthreads();   // waves done with sB stage-1 reads; P written
        #pragma unroll
        for (int i = 0; i < 8; ++i) {
            int ul = (wid * 8 + i) * 64 + lane;
            int row = ul >> 4, u = ul & 15;
            gload16(W2B + (size_t)row * NHID + n1 * 128 + ((u ^ (row & 7)) << 3),
                    sB + (wid * 8 + i) * 1024);
        }
        __syncthreads();
        #pragma unroll
        for (int kk = 0; kk < 4; ++kk) {
            int u = kk * 4 + lq;
            int arow = wid * 16 + l16;
            short8 af = *(const short8*)(sP + arow * 256 + ((u ^ (arow & 7)) << 4));
            short8 bfv[8];
            #pragma unroll
            for (int fn = 0; fn < 8; ++fn) {
                int rw = fn * 16 + l16;
                bfv[fn] = *(const short8*)(sB + rw * 256 + ((u ^ (rw & 7)) << 4));
            }
            #pragma unroll
            for (int fn = 0; fn < 8; ++fn)
                acc2[fn] = __builtin_amdgcn_mfma_f32_16x16x32_bf16(
                    af, bfv[fn], acc2[fn], 0, 0, 0);
        }
    }

    // be = sum_s w_s * b2raw[s][col] into sBe (alias sA), then epilogue
    float* sBe = (float*)sA;
    __syncthreads();
    if (t < 128) {
        float b = 0.f;
        if (t < NCLS) {
            #pragma unroll
            for (int s = 0; s < NSUB; ++s)
                b += F[OFF_W + s] * F[OFF_B2R + s * NCLS + t];
        }
        sBe[t] = b;
    }
    __syncthreads();

    #pragma unroll
    for (int fn = 0; fn < 8; ++fn) {
        int gcol = fn * 16 + l16;
        if (gcol < NCLS) {
            float be = sBe[gcol];
            #pragma unroll
            for (int r = 0; r < 4; ++r) {
                int grow = Row0 + wid * 16 + lq * 4 + r;
                out[(size_t)grow * NCLS + gcol] = acc2[fn][r] + be;
            }
        }
    }
}

// ---------------- launch ----------------
extern "C" void kernel_launch(void* const* d_in, const int* in_sizes, int n_in,
                              void* d_out, int out_size, void* d_ws, size_t ws_size,
                              hipStream_t stream)
{
    const float* x    = (const float*)d_in[0];
    const float* Wh1  = (const float*)d_in[1];
    const float* bh1  = (const float*)d_in[2];
    const float* g1   = (const float*)d_in[3];
    const float* be1  = (const float*)d_in[4];
    const float* Wh2  = (const float*)d_in[5];
    const float* bh2  = (const float*)d_in[6];
    const float* g2   = (const float*)d_in[7];
    const float* be2  = (const float*)d_in[8];
    const float* Wh3  = (const float*)d_in[9];
    const float* bh3  = (const float*)d_in[10];
    const float* ensw = (const float*)d_in[11];
    float* F = (float*)d_ws;
    float* out = (float*)d_out;

    const __hip_bfloat16* XB  = (const __hip_bfloat16*)(F + OFF_XB);
    const __hip_bfloat16* W1B = (const __hip_bfloat16*)(F + OFF_W1B);
    const __hip_bfloat16* W2B = (const __hip_bfloat16*)(F + OFF_W2B);

    k1_colsum<<<512, 256, 0, stream>>>(x, F);
    k2_hyper<<<1, 256, 0, stream>>>(Wh1, bh1, g1, be1, Wh2, bh2, g2, be2, ensw, F);
    k3_gemv<<<NPAR / 8, 256, 0, stream>>>(Wh3, bh3, F);
    // fused: out = relu(XB @ W1B^T + b1) @ W2B^T + be   M=32768, grid 512 x BM=64
    gemm_fused<<<BATCH / 64, 256, 0, stream>>>(XB, W1B, W2B, F, out);
}